// Round 1
// baseline (499.197 us; speedup 1.0000x reference)
//
#include <hip/hip_runtime.h>
#include <math.h>

#define LTOT 131072

typedef unsigned short u16;
typedef unsigned int   u32;
typedef __attribute__((ext_vector_type(8))) short bf16x8;
typedef __attribute__((ext_vector_type(4))) short bf16x4;
typedef __attribute__((ext_vector_type(4))) float f32x4;

__device__ __forceinline__ u16 f2b(float f) {
  union { float f; u32 u; } v; v.f = f;
  u32 r = v.u + 0x7fffu + ((v.u >> 16) & 1u);
  return (u16)(r >> 16);
}

// -------------------------------------------------------------------------
// Kernel 1: QKV projection.  scratch = d_out reinterpreted as bf16:
//   QT: [l][c]  (131072 x 128), scaled by 1/sqrt(128)     offset 0
//   KT: [p][c]  (131072 x 128)                            offset 128*L
//   V : [c][p]  (128 x 131072)                            offset 256*L
// -------------------------------------------------------------------------
__global__ __launch_bounds__(256) void k_qkv(
    const float* __restrict__ x1,
    const float* __restrict__ Wq, const float* __restrict__ bq,
    const float* __restrict__ Wk, const float* __restrict__ bk,
    const float* __restrict__ Wv, const float* __restrict__ bv,
    u16* __restrict__ scratch)
{
  const int XS = 264;   // sXT row stride (k dim), 256+8 pad
  const int WS = 136;   // sW/sT row stride, 128+8 pad
  __shared__ __align__(16) u16 sXT[128 * 264];  // sXT[n][k] = x1[k][l0+n]
  __shared__ __align__(16) u16 sW [128 * 136];  // W rows (also reused as transpose buffer)

  const int tid  = threadIdx.x;
  const int lane = tid & 63;
  const int wv   = tid >> 6;       // 4 waves
  const int lr   = lane & 15;
  const int lg   = lane >> 4;
  const int l0   = blockIdx.x * 128;

  // stage x1^T tile (f32 -> bf16)
  for (int idx = tid; idx < 256 * 32; idx += 256) {
    int k  = idx >> 5;
    int n4 = (idx & 31) << 2;
    float4 v = *reinterpret_cast<const float4*>(x1 + (size_t)k * LTOT + l0 + n4);
    sXT[(n4 + 0) * XS + k] = f2b(v.x);
    sXT[(n4 + 1) * XS + k] = f2b(v.y);
    sXT[(n4 + 2) * XS + k] = f2b(v.z);
    sXT[(n4 + 3) * XS + k] = f2b(v.w);
  }

  const float rs = 0.08838834764831845f;  // 1/sqrt(128)

  for (int wb = 0; wb < 3; ++wb) {
    const float* Wsel = (wb == 0) ? Wq : (wb == 1) ? Wk : Wv;
    const float* bsel = (wb == 0) ? bq : (wb == 1) ? bk : bv;

    f32x4 acc[2][8];
#pragma unroll
    for (int mt = 0; mt < 2; ++mt)
#pragma unroll
      for (int nt = 0; nt < 8; ++nt) acc[mt][nt] = (f32x4){0.f, 0.f, 0.f, 0.f};

    for (int kh = 0; kh < 2; ++kh) {
      __syncthreads();  // previous users of sW done (also orders sXT stage on first pass)
      for (int idx = tid; idx < 128 * 32; idx += 256) {
        int m  = idx >> 5;
        int q4 = (idx & 31) << 2;
        float4 v = *reinterpret_cast<const float4*>(Wsel + m * 256 + kh * 128 + q4);
        bf16x4 s;
        s[0] = (short)f2b(v.x); s[1] = (short)f2b(v.y);
        s[2] = (short)f2b(v.z); s[3] = (short)f2b(v.w);
        *reinterpret_cast<bf16x4*>(&sW[m * WS + q4]) = s;
      }
      __syncthreads();

      const int mBase = wv * 32;
#pragma unroll
      for (int kc = 0; kc < 4; ++kc) {
        const int ka = kc * 32 + (lg << 3);
        const int kb = kh * 128 + ka;
        bf16x8 a0 = *reinterpret_cast<const bf16x8*>(&sW[(mBase + lr) * WS + ka]);
        bf16x8 a1 = *reinterpret_cast<const bf16x8*>(&sW[(mBase + 16 + lr) * WS + ka]);
#pragma unroll
        for (int nt = 0; nt < 8; ++nt) {
          bf16x8 b = *reinterpret_cast<const bf16x8*>(&sXT[(nt * 16 + lr) * XS + kb]);
          acc[0][nt] = __builtin_amdgcn_mfma_f32_16x16x32_bf16(a0, b, acc[0][nt], 0, 0, 0);
          acc[1][nt] = __builtin_amdgcn_mfma_f32_16x16x32_bf16(a1, b, acc[1][nt], 0, 0, 0);
        }
      }
    }
    __syncthreads();  // MFMA reads of sW done; reuse sW as transpose buffer sT
    u16* sT = sW;

    if (wb < 2) {
      // Q / K : write transposed  sT[n][m]  ->  global [l][c]
#pragma unroll
      for (int mt = 0; mt < 2; ++mt) {
        const int m0 = wv * 32 + mt * 16 + (lg << 2);
        float4 b4 = *reinterpret_cast<const float4*>(bsel + m0);
#pragma unroll
        for (int nt = 0; nt < 8; ++nt) {
          const int n = nt * 16 + lr;
          f32x4 d = acc[mt][nt];
          float v0 = d[0] + b4.x, v1 = d[1] + b4.y, v2 = d[2] + b4.z, v3 = d[3] + b4.w;
          if (wb == 0) { v0 *= rs; v1 *= rs; v2 *= rs; v3 *= rs; }
          bf16x4 s;
          s[0] = (short)f2b(v0); s[1] = (short)f2b(v1);
          s[2] = (short)f2b(v2); s[3] = (short)f2b(v3);
          *reinterpret_cast<bf16x4*>(&sT[n * WS + m0]) = s;
        }
      }
      __syncthreads();
      const size_t base = (wb == 0) ? (size_t)0 : (size_t)128 * LTOT;
      for (int idx = tid; idx < 2048; idx += 256) {
        int row = idx >> 4;
        int ch  = (idx & 15) << 3;
        uint4 v = *reinterpret_cast<const uint4*>(&sT[row * WS + ch]);
        *reinterpret_cast<uint4*>(scratch + base + (size_t)(l0 + row) * 128 + ch) = v;
      }
    } else {
      // V : direct  sT[m][n]  ->  global [c][p]
#pragma unroll
      for (int mt = 0; mt < 2; ++mt) {
        const int m0 = wv * 32 + mt * 16 + (lg << 2);
        float4 b4 = *reinterpret_cast<const float4*>(bsel + m0);
#pragma unroll
        for (int nt = 0; nt < 8; ++nt) {
          const int n = nt * 16 + lr;
          f32x4 d = acc[mt][nt];
          sT[(m0 + 0) * WS + n] = f2b(d[0] + b4.x);
          sT[(m0 + 1) * WS + n] = f2b(d[1] + b4.y);
          sT[(m0 + 2) * WS + n] = f2b(d[2] + b4.z);
          sT[(m0 + 3) * WS + n] = f2b(d[3] + b4.w);
        }
      }
      __syncthreads();
      const size_t base = (size_t)256 * LTOT;
      for (int idx = tid; idx < 2048; idx += 256) {
        int row = idx >> 4;
        int ch  = (idx & 15) << 3;
        uint4 v = *reinterpret_cast<const uint4*>(&sT[row * WS + ch]);
        *reinterpret_cast<uint4*>(scratch + base + (size_t)row * LTOT + l0 + ch) = v;
      }
    }
  }
}

// -------------------------------------------------------------------------
// Kernel 2: sliding-window attention, flash-style online softmax.
// Grid: 512 WGs x 512 threads (8 waves, 32 queries/wave, 256 queries/WG).
// Writes relu(att_out)^T as bf16 [l][c] into ws.
// -------------------------------------------------------------------------
__global__ __launch_bounds__(512) void k_attn(
    const u16* __restrict__ scratch,
    const float* __restrict__ mask,
    u16* __restrict__ attT)
{
  __shared__ __align__(16) unsigned char smem[74752];
  u16*   sKT  = (u16*)smem;               // [64][136]   17408 B
  u16*   sV   = (u16*)(smem + 17408);     // [128][72]   18432 B
  float* sFsc = (float*)(smem + 72704);   // [8][32]
  float* sD   = (float*)(smem + 73728);   // [8][32]

  const int tid  = threadIdx.x;
  const int lane = tid & 63;
  const int wv   = tid >> 6;       // 8 waves
  const int lr   = lane & 15;
  const int lg   = lane >> 4;
  const int lq0  = blockIdx.x << 8;          // first query of WG
  const int nblk = lq0 >> 9;                 // 512-block index
  const int p_base = nblk * 512 - 256;       // window start position
  const int wq0  = lq0 + wv * 32;

  const u16* QT = scratch;
  const u16* KT = scratch + (size_t)128 * LTOT;
  const u16* Vp = scratch + (size_t)256 * LTOT;
  u16* sPTw = (u16*)(smem + 35840) + wv * (32 * 72);  // per-wave P tile [32][72]

  // Q fragments (A operand, rows = queries)
  bf16x8 aQ[2][4];
#pragma unroll
  for (int mt = 0; mt < 2; ++mt)
#pragma unroll
    for (int kc = 0; kc < 4; ++kc)
      aQ[mt][kc] = *reinterpret_cast<const bf16x8*>(
          QT + (size_t)(wq0 + mt * 16 + lr) * 128 + kc * 32 + (lg << 3));

  float m_run[2][4], d_run[2][4];
#pragma unroll
  for (int mt = 0; mt < 2; ++mt)
#pragma unroll
    for (int r = 0; r < 4; ++r) { m_run[mt][r] = -INFINITY; d_run[mt][r] = 0.f; }

  f32x4 accO[8][2];
#pragma unroll
  for (int cm = 0; cm < 8; ++cm) {
    accO[cm][0] = (f32x4){0.f, 0.f, 0.f, 0.f};
    accO[cm][1] = (f32x4){0.f, 0.f, 0.f, 0.f};
  }

  for (int it = 0; it < 16; ++it) {
    if (it) __syncthreads();     // prior PV reads done before restaging
    const int p0 = p_base + it * 64;

    for (int idx = tid; idx < 1024; idx += 512) {   // sKT[w][c] <- KT[p0+w][c]
      int row = idx >> 4, ch = (idx & 15) << 3;
      int p = p0 + row;
      uint4 v = make_uint4(0u, 0u, 0u, 0u);
      if (p >= 0 && p < LTOT) v = *reinterpret_cast<const uint4*>(KT + (size_t)p * 128 + ch);
      *reinterpret_cast<uint4*>(&sKT[row * 136 + ch]) = v;
    }
    for (int idx = tid; idx < 1024; idx += 512) {   // sV[c][w] <- V[c][p0+w]
      int c = idx >> 3, ch = (idx & 7) << 3;
      int p = p0 + ch;
      uint4 v = make_uint4(0u, 0u, 0u, 0u);
      if (p >= 0 && p < LTOT) v = *reinterpret_cast<const uint4*>(Vp + (size_t)c * LTOT + p);
      *reinterpret_cast<uint4*>(&sV[c * 72 + ch]) = v;
    }
    __syncthreads();

    // column masks (exact reference semantics: log(fm + 1e-6))
    float logfm_[4], fm_[4];
#pragma unroll
    for (int nt = 0; nt < 4; ++nt) {
      int wl = it * 64 + nt * 16 + lr;     // index inside the 1024 window
      int p  = p_base + wl;
      float fmv = 0.f;
      if (wl < 1023 && p >= 0 && p < LTOT) fmv = mask[p];
      fm_[nt]    = fmv;
      logfm_[nt] = logf(fmv + 1e-6f);
    }

    // E = Q^T K   (rows = queries, cols = window positions)
    f32x4 e[2][4];
#pragma unroll
    for (int mt = 0; mt < 2; ++mt)
#pragma unroll
      for (int nt = 0; nt < 4; ++nt) e[mt][nt] = (f32x4){0.f, 0.f, 0.f, 0.f};
#pragma unroll
    for (int kc = 0; kc < 4; ++kc) {
      const int ko = kc * 32 + (lg << 3);
      bf16x8 b[4];
#pragma unroll
      for (int nt = 0; nt < 4; ++nt)
        b[nt] = *reinterpret_cast<const bf16x8*>(&sKT[(nt * 16 + lr) * 136 + ko]);
#pragma unroll
      for (int mt = 0; mt < 2; ++mt)
#pragma unroll
        for (int nt = 0; nt < 4; ++nt)
          e[mt][nt] = __builtin_amdgcn_mfma_f32_16x16x32_bf16(aQ[mt][kc], b[nt], e[mt][nt], 0, 0, 0);
    }

    // online softmax (per query row; 16-lane group reduce)
#pragma unroll
    for (int mt = 0; mt < 2; ++mt) {
#pragma unroll
      for (int r = 0; r < 4; ++r) {
        float ev0 = e[mt][0][r] + logfm_[0];
        float ev1 = e[mt][1][r] + logfm_[1];
        float ev2 = e[mt][2][r] + logfm_[2];
        float ev3 = e[mt][3][r] + logfm_[3];
        float mx = fmaxf(fmaxf(ev0, ev1), fmaxf(ev2, ev3));
#pragma unroll
        for (int off = 1; off < 16; off <<= 1) mx = fmaxf(mx, __shfl_xor(mx, off));
        float mold = m_run[mt][r];
        float mnew = fmaxf(mold, mx);
        float fs = expf(mold - mnew);
        float pe0 = expf(ev0 - mnew), pe1 = expf(ev1 - mnew);
        float pe2 = expf(ev2 - mnew), pe3 = expf(ev3 - mnew);
        float ps = pe0 + pe1 + pe2 + pe3;
#pragma unroll
        for (int off = 1; off < 16; off <<= 1) ps += __shfl_xor(ps, off);
        d_run[mt][r] = d_run[mt][r] * fs + ps;
        m_run[mt][r] = mnew;
        const int ll = mt * 16 + (lg << 2) + r;
        if (lr == 0) sFsc[wv * 32 + ll] = fs;
        // PV numerator weights: p * fm  (denominator keeps unmasked p)
        sPTw[ll * 72 +      lr] = f2b(pe0 * fm_[0]);
        sPTw[ll * 72 + 16 + lr] = f2b(pe1 * fm_[1]);
        sPTw[ll * 72 + 32 + lr] = f2b(pe2 * fm_[2]);
        sPTw[ll * 72 + 48 + lr] = f2b(pe3 * fm_[3]);
      }
    }
    __syncthreads();

    // rescale accumulator, then PV
    float fc0 = sFsc[wv * 32 + lr];
    float fc1 = sFsc[wv * 32 + 16 + lr];
#pragma unroll
    for (int cm = 0; cm < 8; ++cm)
#pragma unroll
      for (int r = 0; r < 4; ++r) { accO[cm][0][r] *= fc0; accO[cm][1][r] *= fc1; }

#pragma unroll
    for (int k2 = 0; k2 < 2; ++k2) {
      const int ko = k2 * 32 + (lg << 3);
      bf16x8 bp0 = *reinterpret_cast<const bf16x8*>(&sPTw[lr * 72 + ko]);
      bf16x8 bp1 = *reinterpret_cast<const bf16x8*>(&sPTw[(16 + lr) * 72 + ko]);
#pragma unroll
      for (int cm = 0; cm < 8; ++cm) {
        bf16x8 av = *reinterpret_cast<const bf16x8*>(&sV[(cm * 16 + lr) * 72 + ko]);
        accO[cm][0] = __builtin_amdgcn_mfma_f32_16x16x32_bf16(av, bp0, accO[cm][0], 0, 0, 0);
        accO[cm][1] = __builtin_amdgcn_mfma_f32_16x16x32_bf16(av, bp1, accO[cm][1], 0, 0, 0);
      }
    }
  }

  // finalize: /denom, relu, bf16, transpose via LDS, store attT[l][c]
  if (lr == 0) {
#pragma unroll
    for (int mt = 0; mt < 2; ++mt)
#pragma unroll
      for (int r = 0; r < 4; ++r) sD[wv * 32 + mt * 16 + (lg << 2) + r] = d_run[mt][r];
  }
  __syncthreads();   // also guarantees all PV reads done -> can reuse smem
  float rd0 = 1.f / sD[wv * 32 + lr];
  float rd1 = 1.f / sD[wv * 32 + 16 + lr];

  u16* sTw = (u16*)(smem) + wv * (32 * 136);   // per-wave [32][136]
#pragma unroll
  for (int cm = 0; cm < 8; ++cm) {
#pragma unroll
    for (int lt = 0; lt < 2; ++lt) {
      const float rd = lt ? rd1 : rd0;
      bf16x4 s;
#pragma unroll
      for (int r = 0; r < 4; ++r) {
        float v = accO[cm][lt][r] * rd;
        v = fmaxf(v, 0.f);
        s[r] = (short)f2b(v);
      }
      const int ll = lt * 16 + lr;
      *reinterpret_cast<bf16x4*>(&sTw[ll * 136 + cm * 16 + (lg << 2)]) = s;
    }
  }
  __syncthreads();
  for (int idx = lane; idx < 512; idx += 64) {
    int row = idx >> 4, ch = (idx & 15) << 3;
    uint4 v = *reinterpret_cast<const uint4*>(&sTw[row * 136 + ch]);
    *reinterpret_cast<uint4*>(attT + (size_t)(wq0 + row) * 128 + ch) = v;
  }
}

// -------------------------------------------------------------------------
// Kernel 3: out = (Wo @ relu_att + bo) * mask,  fp32.
// -------------------------------------------------------------------------
__global__ __launch_bounds__(256) void k_out(
    const u16* __restrict__ attT,
    const float* __restrict__ Wo, const float* __restrict__ bo,
    const float* __restrict__ mask,
    float* __restrict__ out)
{
  __shared__ __align__(16) u16 sA [128 * 136];
  __shared__ __align__(16) u16 sWo[256 * 136];
  const int tid  = threadIdx.x;
  const int lane = tid & 63;
  const int wv   = tid >> 6;
  const int lr   = lane & 15;
  const int lg   = lane >> 4;
  const int l0   = blockIdx.x << 7;

  for (int idx = tid; idx < 256 * 32; idx += 256) {
    int m = idx >> 5, q4 = (idx & 31) << 2;
    float4 v = *reinterpret_cast<const float4*>(Wo + m * 128 + q4);
    bf16x4 s;
    s[0] = (short)f2b(v.x); s[1] = (short)f2b(v.y);
    s[2] = (short)f2b(v.z); s[3] = (short)f2b(v.w);
    *reinterpret_cast<bf16x4*>(&sWo[m * 136 + q4]) = s;
  }
  for (int idx = tid; idx < 2048; idx += 256) {
    int row = idx >> 4, ch = (idx & 15) << 3;
    uint4 v = *reinterpret_cast<const uint4*>(attT + (size_t)(l0 + row) * 128 + ch);
    *reinterpret_cast<uint4*>(&sA[row * 136 + ch]) = v;
  }
  __syncthreads();

  f32x4 acc[4][8];
#pragma unroll
  for (int mt = 0; mt < 4; ++mt)
#pragma unroll
    for (int nt = 0; nt < 8; ++nt) acc[mt][nt] = (f32x4){0.f, 0.f, 0.f, 0.f};

#pragma unroll
  for (int kc = 0; kc < 4; ++kc) {
    const int ko = kc * 32 + (lg << 3);
    bf16x8 a[4], b[8];
#pragma unroll
    for (int mt = 0; mt < 4; ++mt)
      a[mt] = *reinterpret_cast<const bf16x8*>(&sWo[(wv * 64 + mt * 16 + lr) * 136 + ko]);
#pragma unroll
    for (int nt = 0; nt < 8; ++nt)
      b[nt] = *reinterpret_cast<const bf16x8*>(&sA[(nt * 16 + lr) * 136 + ko]);
#pragma unroll
    for (int mt = 0; mt < 4; ++mt)
#pragma unroll
      for (int nt = 0; nt < 8; ++nt)
        acc[mt][nt] = __builtin_amdgcn_mfma_f32_16x16x32_bf16(a[mt], b[nt], acc[mt][nt], 0, 0, 0);
  }

#pragma unroll
  for (int mt = 0; mt < 4; ++mt) {
    const int o0 = wv * 64 + mt * 16 + (lg << 2);
    float4 b4 = *reinterpret_cast<const float4*>(bo + o0);
#pragma unroll
    for (int nt = 0; nt < 8; ++nt) {
      const int l = l0 + nt * 16 + lr;
      const float mk = mask[l];
      out[(size_t)(o0 + 0) * LTOT + l] = (acc[mt][nt][0] + b4.x) * mk;
      out[(size_t)(o0 + 1) * LTOT + l] = (acc[mt][nt][1] + b4.y) * mk;
      out[(size_t)(o0 + 2) * LTOT + l] = (acc[mt][nt][2] + b4.z) * mk;
      out[(size_t)(o0 + 3) * LTOT + l] = (acc[mt][nt][3] + b4.w) * mk;
    }
  }
}

extern "C" void kernel_launch(void* const* d_in, const int* in_sizes, int n_in,
                              void* d_out, int out_size, void* d_ws, size_t ws_size,
                              hipStream_t stream) {
  (void)in_sizes; (void)n_in; (void)out_size; (void)ws_size;
  const float* x1   = (const float*)d_in[0];
  const float* mask = (const float*)d_in[1];
  const float* Wq   = (const float*)d_in[2];
  const float* bq   = (const float*)d_in[3];
  const float* Wk   = (const float*)d_in[4];
  const float* bk   = (const float*)d_in[5];
  const float* Wv   = (const float*)d_in[6];
  const float* bv   = (const float*)d_in[7];
  const float* Wo   = (const float*)d_in[8];
  const float* bo   = (const float*)d_in[9];

  // d_out (128 MiB fp32) doubles as bf16 QKV scratch (first 96 MiB),
  // fully rewritten by k_out afterwards.  ws holds relu(att)^T bf16 (32 MiB).
  u16* scratch = (u16*)d_out;
  u16* attT    = (u16*)d_ws;
  float* out   = (float*)d_out;

  hipLaunchKernelGGL(k_qkv, dim3(1024), dim3(256), 0, stream,
                     x1, Wq, bq, Wk, bk, Wv, bv, scratch);
  hipLaunchKernelGGL(k_attn, dim3(512), dim3(512), 0, stream,
                     scratch, mask, attT);
  hipLaunchKernelGGL(k_out, dim3(1024), dim3(256), 0, stream,
                     attT, Wo, bo, mask, out);
}

// Round 2
// 394.864 us; speedup vs baseline: 1.2642x; 1.2642x over previous
//
#include <hip/hip_runtime.h>
#include <math.h>

#define LTOT 131072

typedef unsigned short u16;
typedef unsigned int   u32;
typedef __attribute__((ext_vector_type(8))) short bf16x8;
typedef __attribute__((ext_vector_type(4))) short bf16x4;
typedef __attribute__((ext_vector_type(4))) float f32x4;

__device__ __forceinline__ u16 f2b(float f) {
  union { float f; u32 u; } v; v.f = f;
  u32 r = v.u + 0x7fffu + ((v.u >> 16) & 1u);
  return (u16)(r >> 16);
}

__device__ __forceinline__ u32 cvt_pk(float lo, float hi) {
  u32 r;
  asm("v_cvt_pk_bf16_f32 %0, %1, %2" : "=v"(r) : "v"(lo), "v"(hi));
  return r;
}

__device__ __forceinline__ bf16x8 pack_bp(const f32x4 a, const f32x4 b) {
  union { u32 w[4]; bf16x8 v; } u;
  u.w[0] = cvt_pk(a[0], a[1]);
  u.w[1] = cvt_pk(a[2], a[3]);
  u.w[2] = cvt_pk(b[0], b[1]);
  u.w[3] = cvt_pk(b[2], b[3]);
  return u.v;
}

// -------------------------------------------------------------------------
// Kernel 1: QKV projection.  scratch = d_out reinterpreted as bf16:
//   QT: [l][c]  (131072 x 128), scaled by log2(e)/sqrt(128)   offset 0
//   KT: [p][c]  (131072 x 128)                                offset 128*L
//   V : [c][p]  (128 x 131072)                                offset 256*L
// -------------------------------------------------------------------------
__global__ __launch_bounds__(256) void k_qkv(
    const float* __restrict__ x1,
    const float* __restrict__ Wq, const float* __restrict__ bq,
    const float* __restrict__ Wk, const float* __restrict__ bk,
    const float* __restrict__ Wv, const float* __restrict__ bv,
    u16* __restrict__ scratch)
{
  const int XS = 264;
  const int WS = 136;
  __shared__ __align__(16) u16 sXT[128 * 264];
  __shared__ __align__(16) u16 sW [128 * 136];

  const int tid  = threadIdx.x;
  const int lane = tid & 63;
  const int wv   = tid >> 6;
  const int lr   = lane & 15;
  const int lg   = lane >> 4;
  const int l0   = blockIdx.x * 128;

  for (int idx = tid; idx < 256 * 32; idx += 256) {
    int k  = idx >> 5;
    int n4 = (idx & 31) << 2;
    float4 v = *reinterpret_cast<const float4*>(x1 + (size_t)k * LTOT + l0 + n4);
    sXT[(n4 + 0) * XS + k] = f2b(v.x);
    sXT[(n4 + 1) * XS + k] = f2b(v.y);
    sXT[(n4 + 2) * XS + k] = f2b(v.z);
    sXT[(n4 + 3) * XS + k] = f2b(v.w);
  }

  // log2(e)/sqrt(128): softmax runs in exp2 domain downstream
  const float rs = 0.1275174468f;

  for (int wb = 0; wb < 3; ++wb) {
    const float* Wsel = (wb == 0) ? Wq : (wb == 1) ? Wk : Wv;
    const float* bsel = (wb == 0) ? bq : (wb == 1) ? bk : bv;

    f32x4 acc[2][8];
#pragma unroll
    for (int mt = 0; mt < 2; ++mt)
#pragma unroll
      for (int nt = 0; nt < 8; ++nt) acc[mt][nt] = (f32x4){0.f, 0.f, 0.f, 0.f};

    for (int kh = 0; kh < 2; ++kh) {
      __syncthreads();
      for (int idx = tid; idx < 128 * 32; idx += 256) {
        int m  = idx >> 5;
        int q4 = (idx & 31) << 2;
        float4 v = *reinterpret_cast<const float4*>(Wsel + m * 256 + kh * 128 + q4);
        bf16x4 s;
        s[0] = (short)f2b(v.x); s[1] = (short)f2b(v.y);
        s[2] = (short)f2b(v.z); s[3] = (short)f2b(v.w);
        *reinterpret_cast<bf16x4*>(&sW[m * WS + q4]) = s;
      }
      __syncthreads();

      const int mBase = wv * 32;
#pragma unroll
      for (int kc = 0; kc < 4; ++kc) {
        const int ka = kc * 32 + (lg << 3);
        const int kb = kh * 128 + ka;
        bf16x8 a0 = *reinterpret_cast<const bf16x8*>(&sW[(mBase + lr) * WS + ka]);
        bf16x8 a1 = *reinterpret_cast<const bf16x8*>(&sW[(mBase + 16 + lr) * WS + ka]);
#pragma unroll
        for (int nt = 0; nt < 8; ++nt) {
          bf16x8 b = *reinterpret_cast<const bf16x8*>(&sXT[(nt * 16 + lr) * XS + kb]);
          acc[0][nt] = __builtin_amdgcn_mfma_f32_16x16x32_bf16(a0, b, acc[0][nt], 0, 0, 0);
          acc[1][nt] = __builtin_amdgcn_mfma_f32_16x16x32_bf16(a1, b, acc[1][nt], 0, 0, 0);
        }
      }
    }
    __syncthreads();
    u16* sT = sW;

    if (wb < 2) {
#pragma unroll
      for (int mt = 0; mt < 2; ++mt) {
        const int m0 = wv * 32 + mt * 16 + (lg << 2);
        float4 b4 = *reinterpret_cast<const float4*>(bsel + m0);
#pragma unroll
        for (int nt = 0; nt < 8; ++nt) {
          const int n = nt * 16 + lr;
          f32x4 d = acc[mt][nt];
          float v0 = d[0] + b4.x, v1 = d[1] + b4.y, v2 = d[2] + b4.z, v3 = d[3] + b4.w;
          if (wb == 0) { v0 *= rs; v1 *= rs; v2 *= rs; v3 *= rs; }
          bf16x4 s;
          s[0] = (short)f2b(v0); s[1] = (short)f2b(v1);
          s[2] = (short)f2b(v2); s[3] = (short)f2b(v3);
          *reinterpret_cast<bf16x4*>(&sT[n * WS + m0]) = s;
        }
      }
      __syncthreads();
      const size_t base = (wb == 0) ? (size_t)0 : (size_t)128 * LTOT;
      for (int idx = tid; idx < 2048; idx += 256) {
        int row = idx >> 4;
        int ch  = (idx & 15) << 3;
        uint4 v = *reinterpret_cast<const uint4*>(&sT[row * WS + ch]);
        *reinterpret_cast<uint4*>(scratch + base + (size_t)(l0 + row) * 128 + ch) = v;
      }
    } else {
#pragma unroll
      for (int mt = 0; mt < 2; ++mt) {
        const int m0 = wv * 32 + mt * 16 + (lg << 2);
        float4 b4 = *reinterpret_cast<const float4*>(bsel + m0);
#pragma unroll
        for (int nt = 0; nt < 8; ++nt) {
          const int n = nt * 16 + lr;
          f32x4 d = acc[mt][nt];
          sT[(m0 + 0) * WS + n] = f2b(d[0] + b4.x);
          sT[(m0 + 1) * WS + n] = f2b(d[1] + b4.y);
          sT[(m0 + 2) * WS + n] = f2b(d[2] + b4.z);
          sT[(m0 + 3) * WS + n] = f2b(d[3] + b4.w);
        }
      }
      __syncthreads();
      const size_t base = (size_t)256 * LTOT;
      for (int idx = tid; idx < 2048; idx += 256) {
        int row = idx >> 4;
        int ch  = (idx & 15) << 3;
        uint4 v = *reinterpret_cast<const uint4*>(&sT[row * WS + ch]);
        *reinterpret_cast<uint4*>(scratch + base + (size_t)row * LTOT + l0 + ch) = v;
      }
    }
  }
}

// -------------------------------------------------------------------------
// Kernel 2: sliding-window attention, lane-local P (swapped QK^T),
// exp2-domain online softmax with defer-max, custom k-order PV.
// Grid: 1024 WGs x 512 threads; 16 queries/wave, 128 queries/WG.
// -------------------------------------------------------------------------
__global__ __launch_bounds__(512, 4) void k_attn(
    const u16* __restrict__ scratch,
    const float* __restrict__ mask,
    u16* __restrict__ attT)
{
  __shared__ __align__(16) unsigned char smem[44032];
  u16*   sKT = (u16*)smem;               // [64][136]  17408 B
  u16*   sV  = (u16*)(smem + 17408);     // [128][72]  18432 B
  float* sLF = (float*)(smem + 35840);   // [1024] log2(fm+1e-6)
  float* sFM = (float*)(smem + 39936);   // [1024] fm

  const int tid  = threadIdx.x;
  const int lane = tid & 63;
  const int wv   = tid >> 6;
  const int lr   = lane & 15;
  const int lg   = lane >> 4;
  const int lq0  = blockIdx.x << 7;          // 128 queries / WG
  const int nblk = lq0 >> 9;
  const int p_base = nblk * 512 - 256;
  const int wq0  = lq0 + wv * 16;

  const u16* QT = scratch;
  const u16* KT = scratch + (size_t)128 * LTOT;
  const u16* Vp = scratch + (size_t)256 * LTOT;

  // window tables (once per WG): exact semantics log2(fm+1e-6), w<1023
  for (int idx = tid; idx < 1024; idx += 512) {
    int p = p_base + idx;
    float fmv = 0.f;
    if (idx < 1023 && (unsigned)p < (unsigned)LTOT) fmv = mask[p];
    sFM[idx] = fmv;
    sLF[idx] = log2f(fmv + 1e-6f);
  }

  // Q fragments: lane holds Q[query=wq0+lr][ch kc*32+lg*8 ..+8]
  bf16x8 aQ[4];
#pragma unroll
  for (int kc = 0; kc < 4; ++kc)
    aQ[kc] = *reinterpret_cast<const bf16x8*>(
        QT + (size_t)(wq0 + lr) * 128 + kc * 32 + (lg << 3));

  float m_run = -INFINITY;
  f32x4 d4 = (f32x4){0.f, 0.f, 0.f, 0.f};
  f32x4 accO[8];   // [cm]: query=lr, channel=cm*16+4*lg+r
#pragma unroll
  for (int cm = 0; cm < 8; ++cm) accO[cm] = (f32x4){0.f, 0.f, 0.f, 0.f};

  // ---- staging (T14 split: load-early / write-late), single LDS buffer ----
  uint4 rk[2], rv[2];
  {
    const int p0 = p_base;
#pragma unroll
    for (int j = 0; j < 2; ++j) {
      int idx = tid + j * 512;
      int row = idx >> 4, ch = (idx & 15) << 3;
      int p = p0 + row;
      rk[j] = make_uint4(0u, 0u, 0u, 0u);
      if ((unsigned)p < (unsigned)LTOT)
        rk[j] = *reinterpret_cast<const uint4*>(KT + (size_t)p * 128 + ch);
      int c = idx >> 3, w = (idx & 7) << 3;
      int pp = p0 + w;
      rv[j] = make_uint4(0u, 0u, 0u, 0u);
      if ((unsigned)pp < (unsigned)LTOT)
        rv[j] = *reinterpret_cast<const uint4*>(Vp + (size_t)c * LTOT + pp);
    }
  }
#pragma unroll
  for (int j = 0; j < 2; ++j) {
    int idx = tid + j * 512;
    int row = idx >> 4, ch = (idx & 15) << 3;
    *reinterpret_cast<uint4*>(&sKT[row * 136 + ch]) = rk[j];
    int c = idx >> 3, w = (idx & 7) << 3;
    *reinterpret_cast<uint4*>(&sV[c * 72 + w]) = rv[j];
  }
  __syncthreads();

  for (int it = 0; it < 16; ++it) {
    // issue next tile's global loads early; LDS-write after the barrier
    if (it < 15) {
      const int p0 = p_base + (it + 1) * 64;
#pragma unroll
      for (int j = 0; j < 2; ++j) {
        int idx = tid + j * 512;
        int row = idx >> 4, ch = (idx & 15) << 3;
        int p = p0 + row;
        rk[j] = make_uint4(0u, 0u, 0u, 0u);
        if ((unsigned)p < (unsigned)LTOT)
          rk[j] = *reinterpret_cast<const uint4*>(KT + (size_t)p * 128 + ch);
        int c = idx >> 3, w = (idx & 7) << 3;
        int pp = p0 + w;
        rv[j] = make_uint4(0u, 0u, 0u, 0u);
        if ((unsigned)pp < (unsigned)LTOT)
          rv[j] = *reinterpret_cast<const uint4*>(Vp + (size_t)c * LTOT + pp);
      }
    }

    // QK^T swapped: e[nt] = E[pos nt*16+4*lg+r][query lr]
    f32x4 e[4];
#pragma unroll
    for (int nt = 0; nt < 4; ++nt) e[nt] = (f32x4){0.f, 0.f, 0.f, 0.f};
#pragma unroll
    for (int kc = 0; kc < 4; ++kc) {
      const int ko = kc * 32 + (lg << 3);
#pragma unroll
      for (int nt = 0; nt < 4; ++nt) {
        bf16x8 bk = *reinterpret_cast<const bf16x8*>(&sKT[(nt * 16 + lr) * 136 + ko]);
        e[nt] = __builtin_amdgcn_mfma_f32_16x16x32_bf16(bk, aQ[kc], e[nt], 0, 0, 0);
      }
    }

    const int wbase = it * 64 + (lg << 2);
#pragma unroll
    for (int nt = 0; nt < 4; ++nt) {
      f32x4 lf = *reinterpret_cast<const f32x4*>(&sLF[wbase + nt * 16]);
      e[nt] += lf;
    }

    // defer-max online softmax (log2 domain)
    float lmax = e[0][0];
#pragma unroll
    for (int nt = 0; nt < 4; ++nt)
#pragma unroll
      for (int r = 0; r < 4; ++r) if (nt || r) lmax = fmaxf(lmax, e[nt][r]);

    if (__any(lmax > m_run + 12.0f)) {
      float rmax = lmax;
      rmax = fmaxf(rmax, __shfl_xor(rmax, 16));
      rmax = fmaxf(rmax, __shfl_xor(rmax, 32));
      float mnew = fmaxf(m_run, rmax);
      float fs = exp2f(m_run - mnew);
      d4 *= fs;
#pragma unroll
      for (int cm = 0; cm < 8; ++cm) accO[cm] *= fs;
      m_run = mnew;
    }

    f32x4 pn[4];
#pragma unroll
    for (int nt = 0; nt < 4; ++nt) {
      f32x4 fmv = *reinterpret_cast<const f32x4*>(&sFM[wbase + nt * 16]);
      f32x4 pd;
#pragma unroll
      for (int r = 0; r < 4; ++r) pd[r] = exp2f(e[nt][r] - m_run);
      d4 += pd;
      pn[nt] = pd * fmv;   // numerator weights: p * fm
    }
    bf16x8 bp0 = pack_bp(pn[0], pn[1]);
    bf16x8 bp1 = pack_bp(pn[2], pn[3]);

    // PV with custom k-order phi(8g+j)=4g+(j&3)+16(j>>2)+32*k2 on both operands
#pragma unroll
    for (int k2 = 0; k2 < 2; ++k2) {
      const bf16x8 bp = k2 ? bp1 : bp0;
      const int vo = k2 * 32 + (lg << 2);
#pragma unroll
      for (int cm = 0; cm < 8; ++cm) {
        const u16* vr = &sV[(cm * 16 + lr) * 72 + vo];
        bf16x4 v0 = *reinterpret_cast<const bf16x4*>(vr);
        bf16x4 v1 = *reinterpret_cast<const bf16x4*>(vr + 16);
        bf16x8 av = __builtin_shufflevector(v0, v1, 0, 1, 2, 3, 4, 5, 6, 7);
        accO[cm] = __builtin_amdgcn_mfma_f32_16x16x32_bf16(av, bp, accO[cm], 0, 0, 0);
      }
    }

    __syncthreads();
    if (it < 15) {
#pragma unroll
      for (int j = 0; j < 2; ++j) {
        int idx = tid + j * 512;
        int row = idx >> 4, ch = (idx & 15) << 3;
        *reinterpret_cast<uint4*>(&sKT[row * 136 + ch]) = rk[j];
        int c = idx >> 3, w = (idx & 7) << 3;
        *reinterpret_cast<uint4*>(&sV[c * 72 + w]) = rv[j];
      }
    }
    __syncthreads();
  }

  // finalize: denom reduce across the 4 g-lanes, /d, relu, bf16, transpose
  float dsum = d4[0] + d4[1] + d4[2] + d4[3];
  dsum += __shfl_xor(dsum, 16);
  dsum += __shfl_xor(dsum, 32);
  const float rd = 1.f / dsum;

  __syncthreads();
  u16* sT = (u16*)smem + wv * 2176;   // per-wave [16][136]
#pragma unroll
  for (int cm = 0; cm < 8; ++cm) {
    float o0 = fmaxf(accO[cm][0] * rd, 0.f);
    float o1 = fmaxf(accO[cm][1] * rd, 0.f);
    float o2 = fmaxf(accO[cm][2] * rd, 0.f);
    float o3 = fmaxf(accO[cm][3] * rd, 0.f);
    uint2 pk = make_uint2(cvt_pk(o0, o1), cvt_pk(o2, o3));
    *reinterpret_cast<uint2*>(&sT[lr * 136 + cm * 16 + (lg << 2)]) = pk;
  }
  __syncthreads();
  for (int idx = lane; idx < 256; idx += 64) {
    int row = idx >> 4, ch = (idx & 15) << 3;
    uint4 v = *reinterpret_cast<const uint4*>(&sT[row * 136 + ch]);
    *reinterpret_cast<uint4*>(attT + (size_t)(wq0 + row) * 128 + ch) = v;
  }
}

// -------------------------------------------------------------------------
// Kernel 3: out = (Wo @ relu_att + bo) * mask,  fp32.
// -------------------------------------------------------------------------
__global__ __launch_bounds__(256) void k_out(
    const u16* __restrict__ attT,
    const float* __restrict__ Wo, const float* __restrict__ bo,
    const float* __restrict__ mask,
    float* __restrict__ out)
{
  __shared__ __align__(16) u16 sA [128 * 136];
  __shared__ __align__(16) u16 sWo[256 * 136];
  const int tid  = threadIdx.x;
  const int lane = tid & 63;
  const int wv   = tid >> 6;
  const int lr   = lane & 15;
  const int lg   = lane >> 4;
  const int l0   = blockIdx.x << 7;

  for (int idx = tid; idx < 256 * 32; idx += 256) {
    int m = idx >> 5, q4 = (idx & 31) << 2;
    float4 v = *reinterpret_cast<const float4*>(Wo + m * 128 + q4);
    bf16x4 s;
    s[0] = (short)f2b(v.x); s[1] = (short)f2b(v.y);
    s[2] = (short)f2b(v.z); s[3] = (short)f2b(v.w);
    *reinterpret_cast<bf16x4*>(&sWo[m * 136 + q4]) = s;
  }
  for (int idx = tid; idx < 2048; idx += 256) {
    int row = idx >> 4, ch = (idx & 15) << 3;
    uint4 v = *reinterpret_cast<const uint4*>(attT + (size_t)(l0 + row) * 128 + ch);
    *reinterpret_cast<uint4*>(&sA[row * 136 + ch]) = v;
  }
  __syncthreads();

  f32x4 acc[4][8];
#pragma unroll
  for (int mt = 0; mt < 4; ++mt)
#pragma unroll
    for (int nt = 0; nt < 8; ++nt) acc[mt][nt] = (f32x4){0.f, 0.f, 0.f, 0.f};

#pragma unroll
  for (int kc = 0; kc < 4; ++kc) {
    const int ko = kc * 32 + (lg << 3);
    bf16x8 a[4], b[8];
#pragma unroll
    for (int mt = 0; mt < 4; ++mt)
      a[mt] = *reinterpret_cast<const bf16x8*>(&sWo[(wv * 64 + mt * 16 + lr) * 136 + ko]);
#pragma unroll
    for (int nt = 0; nt < 8; ++nt)
      b[nt] = *reinterpret_cast<const bf16x8*>(&sA[(nt * 16 + lr) * 136 + ko]);
#pragma unroll
    for (int mt = 0; mt < 4; ++mt)
#pragma unroll
      for (int nt = 0; nt < 8; ++nt)
        acc[mt][nt] = __builtin_amdgcn_mfma_f32_16x16x32_bf16(a[mt], b[nt], acc[mt][nt], 0, 0, 0);
  }

#pragma unroll
  for (int mt = 0; mt < 4; ++mt) {
    const int o0 = wv * 64 + mt * 16 + (lg << 2);
    float4 b4 = *reinterpret_cast<const float4*>(bo + o0);
#pragma unroll
    for (int nt = 0; nt < 8; ++nt) {
      const int l = l0 + nt * 16 + lr;
      const float mk = mask[l];
      out[(size_t)(o0 + 0) * LTOT + l] = (acc[mt][nt][0] + b4.x) * mk;
      out[(size_t)(o0 + 1) * LTOT + l] = (acc[mt][nt][1] + b4.y) * mk;
      out[(size_t)(o0 + 2) * LTOT + l] = (acc[mt][nt][2] + b4.z) * mk;
      out[(size_t)(o0 + 3) * LTOT + l] = (acc[mt][nt][3] + b4.w) * mk;
    }
  }
}

extern "C" void kernel_launch(void* const* d_in, const int* in_sizes, int n_in,
                              void* d_out, int out_size, void* d_ws, size_t ws_size,
                              hipStream_t stream) {
  (void)in_sizes; (void)n_in; (void)out_size; (void)ws_size;
  const float* x1   = (const float*)d_in[0];
  const float* mask = (const float*)d_in[1];
  const float* Wq   = (const float*)d_in[2];
  const float* bq   = (const float*)d_in[3];
  const float* Wk   = (const float*)d_in[4];
  const float* bk   = (const float*)d_in[5];
  const float* Wv   = (const float*)d_in[6];
  const float* bv   = (const float*)d_in[7];
  const float* Wo   = (const float*)d_in[8];
  const float* bo   = (const float*)d_in[9];

  u16* scratch = (u16*)d_out;   // d_out doubles as bf16 QKV scratch
  u16* attT    = (u16*)d_ws;
  float* out   = (float*)d_out;

  hipLaunchKernelGGL(k_qkv, dim3(1024), dim3(256), 0, stream,
                     x1, Wq, bq, Wk, bk, Wv, bv, scratch);
  hipLaunchKernelGGL(k_attn, dim3(1024), dim3(512), 0, stream,
                     scratch, mask, attT);
  hipLaunchKernelGGL(k_out, dim3(1024), dim3(256), 0, stream,
                     attT, Wo, bo, mask, out);
}

// Round 4
// 283.280 us; speedup vs baseline: 1.7622x; 1.3939x over previous
//
#include <hip/hip_runtime.h>
#include <math.h>

#define LTOT 131072

typedef unsigned short u16;
typedef unsigned int   u32;
typedef __attribute__((ext_vector_type(8))) short bf16x8;
typedef __attribute__((ext_vector_type(4))) short bf16x4;
typedef __attribute__((ext_vector_type(4))) float f32x4;

__device__ __forceinline__ u16 f2b(float f) {
  union { float f; u32 u; } v; v.f = f;
  u32 r = v.u + 0x7fffu + ((v.u >> 16) & 1u);
  return (u16)(r >> 16);
}

// NOTE: v_cvt_pk_bf16_f32 is NOT round-to-nearest-even (R3 post-mortem:
// using it on GEMM inputs tripled output error). Use ONLY for softmax P
// and final outputs; use f2b (RTNE) for anything entering a long dot.
__device__ __forceinline__ u32 cvt_pk(float lo, float hi) {
  u32 r;
  asm("v_cvt_pk_bf16_f32 %0, %1, %2" : "=v"(r) : "v"(lo), "v"(hi));
  return r;
}

__device__ __forceinline__ bf16x8 pack_bp(const f32x4 a, const f32x4 b) {
  union { u32 w[4]; bf16x8 v; } u;
  u.w[0] = cvt_pk(a[0], a[1]);
  u.w[1] = cvt_pk(a[2], a[3]);
  u.w[2] = cvt_pk(b[0], b[1]);
  u.w[3] = cvt_pk(b[2], b[3]);
  return u.v;
}

// =========================================================================
// Kernel 1: QKV projection.
//   Grid 1024 x 512 threads, 128-column tile per WG, 64 KiB LDS (2 WG/CU),
//   ONE barrier. x1^T staged swizzled in LDS; W read from global (L2).
//   All GEMM-input bf16 conversions via f2b (RTNE).
//   Outputs (bf16 in scratch = d_out):
//     QT [l][c] * log2(e)/sqrt(128)   @ 0
//     KT [p][c]                       @ 128*L
//     V  [c][p]                       @ 256*L
// =========================================================================
__device__ __forceinline__ int sxt_addr(int row, int g) {
  return (row << 8) + (((g) ^ (row & 7)) << 3);
}

__global__ __launch_bounds__(512) void k_qkv(
    const float* __restrict__ x1,
    const float* __restrict__ Wq, const float* __restrict__ bq,
    const float* __restrict__ Wk, const float* __restrict__ bk,
    const float* __restrict__ Wv, const float* __restrict__ bv,
    u16* __restrict__ scratch)
{
  __shared__ __align__(16) u16 sXT[128 * 256];   // [l][k] swizzled, 64 KiB

  const int tid  = threadIdx.x;
  const int lane = tid & 63;
  const int wv   = tid >> 6;        // 8 waves
  const int lr   = lane & 15;
  const int lg   = lane >> 4;
  const int l0   = blockIdx.x << 7;

  // ---- stage x1^T tile: thread owns 2 columns, 32 k (RTNE pack) ----
  {
    const int cl = (tid & 63) << 1;
    const int kq = tid >> 6;
#pragma unroll
    for (int k8 = 0; k8 < 4; ++k8) {
      const int k0 = kq * 32 + k8 * 8;
      float2 v[8];
#pragma unroll
      for (int j = 0; j < 8; ++j)
        v[j] = *reinterpret_cast<const float2*>(x1 + (size_t)(k0 + j) * LTOT + l0 + cl);
      union { u16 h[8]; bf16x8 b; } p0, p1;
#pragma unroll
      for (int j = 0; j < 8; ++j) {
        p0.h[j] = f2b(v[j].x);
        p1.h[j] = f2b(v[j].y);
      }
      const int g = k0 >> 3;
      *reinterpret_cast<bf16x8*>(&sXT[sxt_addr(cl,     g)]) = p0.b;
      *reinterpret_cast<bf16x8*>(&sXT[sxt_addr(cl + 1, g)]) = p1.b;
    }
  }
  __syncthreads();

  const float rs = 0.1275174468f;   // log2(e)/sqrt(128)

  // ---- Q and K:  C[l][c] = x1^T @ W^T ; wave owns 16 c ----
#pragma unroll
  for (int wb = 0; wb < 2; ++wb) {
    const float* Wsel = wb ? Wk : Wq;
    const float* bsel = wb ? bk : bq;
    const int c = (wv << 4) + lr;

    bf16x8 bw[8];
    {
      const float* wrow = Wsel + (size_t)c * 256 + (lg << 3);
#pragma unroll
      for (int kc = 0; kc < 8; ++kc) {
        float4 wa = *reinterpret_cast<const float4*>(wrow + kc * 32);
        float4 wc = *reinterpret_cast<const float4*>(wrow + kc * 32 + 4);
        union { u16 h[8]; bf16x8 b; } u;
        u.h[0] = f2b(wa.x); u.h[1] = f2b(wa.y); u.h[2] = f2b(wa.z); u.h[3] = f2b(wa.w);
        u.h[4] = f2b(wc.x); u.h[5] = f2b(wc.y); u.h[6] = f2b(wc.z); u.h[7] = f2b(wc.w);
        bw[kc] = u.b;
      }
    }

    f32x4 acc[8];
#pragma unroll
    for (int mt = 0; mt < 8; ++mt) acc[mt] = (f32x4){0.f, 0.f, 0.f, 0.f};
#pragma unroll
    for (int kc = 0; kc < 8; ++kc) {
      const int g = (kc << 2) + lg;
#pragma unroll
      for (int mt = 0; mt < 8; ++mt) {
        bf16x8 a = *reinterpret_cast<const bf16x8*>(&sXT[sxt_addr((mt << 4) + lr, g)]);
        acc[mt] = __builtin_amdgcn_mfma_f32_16x16x32_bf16(a, bw[kc], acc[mt], 0, 0, 0);
      }
    }

    const float bias = bsel[c];
    const float scale = wb ? 1.f : rs;
    u16* dst = scratch + (size_t)wb * 128 * LTOT;
#pragma unroll
    for (int mt = 0; mt < 8; ++mt) {
      const int l = l0 + (mt << 4) + (lg << 2);
#pragma unroll
      for (int r = 0; r < 4; ++r)
        dst[(size_t)(l + r) * 128 + c] = f2b((acc[mt][r] + bias) * scale);
    }
  }

  // ---- V:  C[c][p] = W @ x1 ; wave owns 16 c-rows ----
  {
    const int c = (wv << 4) + lr;
    bf16x8 aw[8];
    {
      const float* wrow = Wv + (size_t)c * 256 + (lg << 3);
#pragma unroll
      for (int kc = 0; kc < 8; ++kc) {
        float4 wa = *reinterpret_cast<const float4*>(wrow + kc * 32);
        float4 wc = *reinterpret_cast<const float4*>(wrow + kc * 32 + 4);
        union { u16 h[8]; bf16x8 b; } u;
        u.h[0] = f2b(wa.x); u.h[1] = f2b(wa.y); u.h[2] = f2b(wa.z); u.h[3] = f2b(wa.w);
        u.h[4] = f2b(wc.x); u.h[5] = f2b(wc.y); u.h[6] = f2b(wc.z); u.h[7] = f2b(wc.w);
        aw[kc] = u.b;
      }
    }

    f32x4 acc[8];
#pragma unroll
    for (int nt = 0; nt < 8; ++nt) acc[nt] = (f32x4){0.f, 0.f, 0.f, 0.f};
#pragma unroll
    for (int kc = 0; kc < 8; ++kc) {
      const int g = (kc << 2) + lg;
#pragma unroll
      for (int nt = 0; nt < 8; ++nt) {
        bf16x8 b = *reinterpret_cast<const bf16x8*>(&sXT[sxt_addr((nt << 4) + lr, g)]);
        acc[nt] = __builtin_amdgcn_mfma_f32_16x16x32_bf16(aw[kc], b, acc[nt], 0, 0, 0);
      }
    }

    const int c0 = (wv << 4) + (lg << 2);
    float4 bv4 = *reinterpret_cast<const float4*>(bv + c0);
    u16* dstv = scratch + (size_t)256 * LTOT;
#pragma unroll
    for (int nt = 0; nt < 8; ++nt) {
      const int p = l0 + (nt << 4) + lr;
      dstv[(size_t)(c0 + 0) * LTOT + p] = f2b(acc[nt][0] + bv4.x);
      dstv[(size_t)(c0 + 1) * LTOT + p] = f2b(acc[nt][1] + bv4.y);
      dstv[(size_t)(c0 + 2) * LTOT + p] = f2b(acc[nt][2] + bv4.z);
      dstv[(size_t)(c0 + 3) * LTOT + p] = f2b(acc[nt][3] + bv4.w);
    }
  }
}

// -------------------------------------------------------------------------
// Kernel 2: sliding-window attention (unchanged from R2).
// -------------------------------------------------------------------------
__global__ __launch_bounds__(512, 4) void k_attn(
    const u16* __restrict__ scratch,
    const float* __restrict__ mask,
    u16* __restrict__ attT)
{
  __shared__ __align__(16) unsigned char smem[44032];
  u16*   sKT = (u16*)smem;               // [64][136]  17408 B
  u16*   sV  = (u16*)(smem + 17408);     // [128][72]  18432 B
  float* sLF = (float*)(smem + 35840);   // [1024] log2(fm+1e-6)
  float* sFM = (float*)(smem + 39936);   // [1024] fm

  const int tid  = threadIdx.x;
  const int lane = tid & 63;
  const int wv   = tid >> 6;
  const int lr   = lane & 15;
  const int lg   = lane >> 4;
  const int lq0  = blockIdx.x << 7;
  const int nblk = lq0 >> 9;
  const int p_base = nblk * 512 - 256;
  const int wq0  = lq0 + wv * 16;

  const u16* QT = scratch;
  const u16* KT = scratch + (size_t)128 * LTOT;
  const u16* Vp = scratch + (size_t)256 * LTOT;

  for (int idx = tid; idx < 1024; idx += 512) {
    int p = p_base + idx;
    float fmv = 0.f;
    if (idx < 1023 && (unsigned)p < (unsigned)LTOT) fmv = mask[p];
    sFM[idx] = fmv;
    sLF[idx] = log2f(fmv + 1e-6f);
  }

  bf16x8 aQ[4];
#pragma unroll
  for (int kc = 0; kc < 4; ++kc)
    aQ[kc] = *reinterpret_cast<const bf16x8*>(
        QT + (size_t)(wq0 + lr) * 128 + kc * 32 + (lg << 3));

  float m_run = -INFINITY;
  f32x4 d4 = (f32x4){0.f, 0.f, 0.f, 0.f};
  f32x4 accO[8];
#pragma unroll
  for (int cm = 0; cm < 8; ++cm) accO[cm] = (f32x4){0.f, 0.f, 0.f, 0.f};

  uint4 rk[2], rv[2];
  {
    const int p0 = p_base;
#pragma unroll
    for (int j = 0; j < 2; ++j) {
      int idx = tid + j * 512;
      int row = idx >> 4, ch = (idx & 15) << 3;
      int p = p0 + row;
      rk[j] = make_uint4(0u, 0u, 0u, 0u);
      if ((unsigned)p < (unsigned)LTOT)
        rk[j] = *reinterpret_cast<const uint4*>(KT + (size_t)p * 128 + ch);
      int c = idx >> 3, w = (idx & 7) << 3;
      int pp = p0 + w;
      rv[j] = make_uint4(0u, 0u, 0u, 0u);
      if ((unsigned)pp < (unsigned)LTOT)
        rv[j] = *reinterpret_cast<const uint4*>(Vp + (size_t)c * LTOT + pp);
    }
  }
#pragma unroll
  for (int j = 0; j < 2; ++j) {
    int idx = tid + j * 512;
    int row = idx >> 4, ch = (idx & 15) << 3;
    *reinterpret_cast<uint4*>(&sKT[row * 136 + ch]) = rk[j];
    int c = idx >> 3, w = (idx & 7) << 3;
    *reinterpret_cast<uint4*>(&sV[c * 72 + w]) = rv[j];
  }
  __syncthreads();

  for (int it = 0; it < 16; ++it) {
    if (it < 15) {
      const int p0 = p_base + (it + 1) * 64;
#pragma unroll
      for (int j = 0; j < 2; ++j) {
        int idx = tid + j * 512;
        int row = idx >> 4, ch = (idx & 15) << 3;
        int p = p0 + row;
        rk[j] = make_uint4(0u, 0u, 0u, 0u);
        if ((unsigned)p < (unsigned)LTOT)
          rk[j] = *reinterpret_cast<const uint4*>(KT + (size_t)p * 128 + ch);
        int c = idx >> 3, w = (idx & 7) << 3;
        int pp = p0 + w;
        rv[j] = make_uint4(0u, 0u, 0u, 0u);
        if ((unsigned)pp < (unsigned)LTOT)
          rv[j] = *reinterpret_cast<const uint4*>(Vp + (size_t)c * LTOT + pp);
      }
    }

    f32x4 e[4];
#pragma unroll
    for (int nt = 0; nt < 4; ++nt) e[nt] = (f32x4){0.f, 0.f, 0.f, 0.f};
#pragma unroll
    for (int kc = 0; kc < 4; ++kc) {
      const int ko = kc * 32 + (lg << 3);
#pragma unroll
      for (int nt = 0; nt < 4; ++nt) {
        bf16x8 bk = *reinterpret_cast<const bf16x8*>(&sKT[(nt * 16 + lr) * 136 + ko]);
        e[nt] = __builtin_amdgcn_mfma_f32_16x16x32_bf16(bk, aQ[kc], e[nt], 0, 0, 0);
      }
    }

    const int wbase = it * 64 + (lg << 2);
#pragma unroll
    for (int nt = 0; nt < 4; ++nt) {
      f32x4 lf = *reinterpret_cast<const f32x4*>(&sLF[wbase + nt * 16]);
      e[nt] += lf;
    }

    float lmax = e[0][0];
#pragma unroll
    for (int nt = 0; nt < 4; ++nt)
#pragma unroll
      for (int r = 0; r < 4; ++r) if (nt || r) lmax = fmaxf(lmax, e[nt][r]);

    if (__any(lmax > m_run + 12.0f)) {
      float rmax = lmax;
      rmax = fmaxf(rmax, __shfl_xor(rmax, 16));
      rmax = fmaxf(rmax, __shfl_xor(rmax, 32));
      float mnew = fmaxf(m_run, rmax);
      float fs = exp2f(m_run - mnew);
      d4 *= fs;
#pragma unroll
      for (int cm = 0; cm < 8; ++cm) accO[cm] *= fs;
      m_run = mnew;
    }

    f32x4 pn[4];
#pragma unroll
    for (int nt = 0; nt < 4; ++nt) {
      f32x4 fmv = *reinterpret_cast<const f32x4*>(&sFM[wbase + nt * 16]);
      f32x4 pd;
#pragma unroll
      for (int r = 0; r < 4; ++r) pd[r] = exp2f(e[nt][r] - m_run);
      d4 += pd;
      pn[nt] = pd * fmv;
    }
    bf16x8 bp0 = pack_bp(pn[0], pn[1]);
    bf16x8 bp1 = pack_bp(pn[2], pn[3]);

#pragma unroll
    for (int k2 = 0; k2 < 2; ++k2) {
      const bf16x8 bp = k2 ? bp1 : bp0;
      const int vo = k2 * 32 + (lg << 2);
#pragma unroll
      for (int cm = 0; cm < 8; ++cm) {
        const u16* vr = &sV[(cm * 16 + lr) * 72 + vo];
        bf16x4 v0 = *reinterpret_cast<const bf16x4*>(vr);
        bf16x4 v1 = *reinterpret_cast<const bf16x4*>(vr + 16);
        bf16x8 av = __builtin_shufflevector(v0, v1, 0, 1, 2, 3, 4, 5, 6, 7);
        accO[cm] = __builtin_amdgcn_mfma_f32_16x16x32_bf16(av, bp, accO[cm], 0, 0, 0);
      }
    }

    __syncthreads();
    if (it < 15) {
#pragma unroll
      for (int j = 0; j < 2; ++j) {
        int idx = tid + j * 512;
        int row = idx >> 4, ch = (idx & 15) << 3;
        *reinterpret_cast<uint4*>(&sKT[row * 136 + ch]) = rk[j];
        int c = idx >> 3, w = (idx & 7) << 3;
        *reinterpret_cast<uint4*>(&sV[c * 72 + w]) = rv[j];
      }
    }
    __syncthreads();
  }

  float dsum = d4[0] + d4[1] + d4[2] + d4[3];
  dsum += __shfl_xor(dsum, 16);
  dsum += __shfl_xor(dsum, 32);
  const float rd = 1.f / dsum;

  __syncthreads();
  u16* sT = (u16*)smem + wv * 2176;
#pragma unroll
  for (int cm = 0; cm < 8; ++cm) {
    float o0 = fmaxf(accO[cm][0] * rd, 0.f);
    float o1 = fmaxf(accO[cm][1] * rd, 0.f);
    float o2 = fmaxf(accO[cm][2] * rd, 0.f);
    float o3 = fmaxf(accO[cm][3] * rd, 0.f);
    uint2 pk = make_uint2(cvt_pk(o0, o1), cvt_pk(o2, o3));
    *reinterpret_cast<uint2*>(&sT[lr * 136 + cm * 16 + (lg << 2)]) = pk;
  }
  __syncthreads();
  for (int idx = lane; idx < 256; idx += 64) {
    int row = idx >> 4, ch = (idx & 15) << 3;
    uint4 v = *reinterpret_cast<const uint4*>(&sT[row * 136 + ch]);
    *reinterpret_cast<uint4*>(attT + (size_t)(wq0 + row) * 128 + ch) = v;
  }
}

// -------------------------------------------------------------------------
// Kernel 3: out = (Wo @ relu_att + bo) * mask, fp32 (unchanged).
// -------------------------------------------------------------------------
__global__ __launch_bounds__(256) void k_out(
    const u16* __restrict__ attT,
    const float* __restrict__ Wo, const float* __restrict__ bo,
    const float* __restrict__ mask,
    float* __restrict__ out)
{
  __shared__ __align__(16) u16 sA [128 * 136];
  __shared__ __align__(16) u16 sWo[256 * 136];
  const int tid  = threadIdx.x;
  const int lane = tid & 63;
  const int wv   = tid >> 6;
  const int lr   = lane & 15;
  const int lg   = lane >> 4;
  const int l0   = blockIdx.x << 7;

  for (int idx = tid; idx < 256 * 32; idx += 256) {
    int m = idx >> 5, q4 = (idx & 31) << 2;
    float4 v = *reinterpret_cast<const float4*>(Wo + m * 128 + q4);
    bf16x4 s;
    s[0] = (short)f2b(v.x); s[1] = (short)f2b(v.y);
    s[2] = (short)f2b(v.z); s[3] = (short)f2b(v.w);
    *reinterpret_cast<bf16x4*>(&sWo[m * 136 + q4]) = s;
  }
  for (int idx = tid; idx < 2048; idx += 256) {
    int row = idx >> 4, ch = (idx & 15) << 3;
    uint4 v = *reinterpret_cast<const uint4*>(attT + (size_t)(l0 + row) * 128 + ch);
    *reinterpret_cast<uint4*>(&sA[row * 136 + ch]) = v;
  }
  __syncthreads();

  f32x4 acc[4][8];
#pragma unroll
  for (int mt = 0; mt < 4; ++mt)
#pragma unroll
    for (int nt = 0; nt < 8; ++nt) acc[mt][nt] = (f32x4){0.f, 0.f, 0.f, 0.f};

#pragma unroll
  for (int kc = 0; kc < 4; ++kc) {
    const int ko = kc * 32 + (lg << 3);
    bf16x8 a[4], b[8];
#pragma unroll
    for (int mt = 0; mt < 4; ++mt)
      a[mt] = *reinterpret_cast<const bf16x8*>(&sWo[(wv * 64 + mt * 16 + lr) * 136 + ko]);
#pragma unroll
    for (int nt = 0; nt < 8; ++nt)
      b[nt] = *reinterpret_cast<const bf16x8*>(&sA[(nt * 16 + lr) * 136 + ko]);
#pragma unroll
    for (int mt = 0; mt < 4; ++mt)
#pragma unroll
      for (int nt = 0; nt < 8; ++nt)
        acc[mt][nt] = __builtin_amdgcn_mfma_f32_16x16x32_bf16(a[mt], b[nt], acc[mt][nt], 0, 0, 0);
  }

#pragma unroll
  for (int mt = 0; mt < 4; ++mt) {
    const int o0 = wv * 64 + mt * 16 + (lg << 2);
    float4 b4 = *reinterpret_cast<const float4*>(bo + o0);
#pragma unroll
    for (int nt = 0; nt < 8; ++nt) {
      const int l = l0 + nt * 16 + lr;
      const float mk = mask[l];
      out[(size_t)(o0 + 0) * LTOT + l] = (acc[mt][nt][0] + b4.x) * mk;
      out[(size_t)(o0 + 1) * LTOT + l] = (acc[mt][nt][1] + b4.y) * mk;
      out[(size_t)(o0 + 2) * LTOT + l] = (acc[mt][nt][2] + b4.z) * mk;
      out[(size_t)(o0 + 3) * LTOT + l] = (acc[mt][nt][3] + b4.w) * mk;
    }
  }
}

extern "C" void kernel_launch(void* const* d_in, const int* in_sizes, int n_in,
                              void* d_out, int out_size, void* d_ws, size_t ws_size,
                              hipStream_t stream) {
  (void)in_sizes; (void)n_in; (void)out_size; (void)ws_size;
  const float* x1   = (const float*)d_in[0];
  const float* mask = (const float*)d_in[1];
  const float* Wq   = (const float*)d_in[2];
  const float* bq   = (const float*)d_in[3];
  const float* Wk   = (const float*)d_in[4];
  const float* bk   = (const float*)d_in[5];
  const float* Wv   = (const float*)d_in[6];
  const float* bv   = (const float*)d_in[7];
  const float* Wo   = (const float*)d_in[8];
  const float* bo   = (const float*)d_in[9];

  u16* scratch = (u16*)d_out;   // d_out doubles as bf16 QKV scratch
  u16* attT    = (u16*)d_ws;
  float* out   = (float*)d_out;

  hipLaunchKernelGGL(k_qkv, dim3(1024), dim3(512), 0, stream,
                     x1, Wq, bq, Wk, bk, Wv, bv, scratch);
  hipLaunchKernelGGL(k_attn, dim3(1024), dim3(512), 0, stream,
                     scratch, mask, attT);
  hipLaunchKernelGGL(k_out, dim3(1024), dim3(256), 0, stream,
                     attT, Wo, bo, mask, out);
}